// Round 9
// baseline (339.285 us; speedup 1.0000x reference)
//
#include <hip/hip_runtime.h>
#include <stdint.h>

typedef unsigned short u16;
typedef __attribute__((ext_vector_type(8))) short bf16x8;
typedef __attribute__((ext_vector_type(4))) float f32x4;

__device__ __forceinline__ u16 f2bf(float f) {
  union { float f; unsigned u; } x; x.f = f;
  unsigned r = x.u + 0x7fffu + ((x.u >> 16) & 1u);
  return (u16)(r >> 16);
}

__device__ __forceinline__ float gelu_fast(float v) {
  float y = 0.7978845608f * (v + 0.044715f * v * v * v);
  float e = __expf(2.0f * y);
  float th = 1.0f - 2.0f / (e + 1.0f);
  return 0.5f * v * (1.0f + th);
}

#define GLOAD16(g, l) __builtin_amdgcn_global_load_lds( \
    (const __attribute__((address_space(1))) unsigned int*)(g), \
    (__attribute__((address_space(3))) unsigned int*)(l), 16, 0, 0)

// ---------------- fused pre-pass: 4 weight transposes + LN1 ----------------
// flat grid 16384: [0,3072) qkvw, [3072,4096) projw, [4096,8192) fc1w,
// [8192,12288) fc2w, [12288,16384) ln1. Branch is block-uniform.
__global__ __launch_bounds__(256) void pre_kernel(
    const float* __restrict__ qkv_w, const float* __restrict__ proj_w,
    const float* __restrict__ fc1_w, const float* __restrict__ fc2_w,
    u16* __restrict__ qkvw_t, u16* __restrict__ projw_t,
    u16* __restrict__ fc1w_t, u16* __restrict__ fc2w_t,
    const float* __restrict__ x, const float* __restrict__ g,
    const float* __restrict__ be, u16* __restrict__ h1) {
  __shared__ float tile[32][33];
  __shared__ float p1[4], p2[4];
  const int bid = blockIdx.x, t = threadIdx.x;
  if (bid < 12288) {
    const float* W; u16* Wt; int K, N, base, nb;
    if (bid < 3072)      { W = qkv_w;  Wt = qkvw_t;  K = 1024; N = 3072; base = 0;    nb = 96; }
    else if (bid < 4096) { W = proj_w; Wt = projw_t; K = 1024; N = 1024; base = 3072; nb = 32; }
    else if (bid < 8192) { W = fc1_w;  Wt = fc1w_t;  K = 1024; N = 4096; base = 4096; nb = 128; }
    else                 { W = fc2_w;  Wt = fc2w_t;  K = 4096; N = 1024; base = 8192; nb = 32; }
    int r = bid - base;
    int n0 = (r % nb) * 32, k0 = (r / nb) * 32;
    int tx = t & 31, ty = t >> 5;
#pragma unroll
    for (int i = 0; i < 32; i += 8)
      tile[ty + i][tx] = W[(size_t)(k0 + ty + i) * N + n0 + tx];
    __syncthreads();
#pragma unroll
    for (int i = 0; i < 32; i += 8)
      Wt[(size_t)(n0 + ty + i) * K + k0 + tx] = f2bf(tile[tx][ty + i]);
  } else {
    int row = bid - 12288;
    const float4 v = ((const float4*)(x + (size_t)row * 1024))[t];
    float s = v.x + v.y + v.z + v.w;
#pragma unroll
    for (int m = 1; m < 64; m <<= 1) s += __shfl_xor(s, m);
    int wid = t >> 6, lane = t & 63;
    if (lane == 0) p1[wid] = s;
    __syncthreads();
    float mean = (p1[0] + p1[1] + p1[2] + p1[3]) * (1.f / 1024.f);
    float a0 = v.x - mean, a1 = v.y - mean, a2 = v.z - mean, a3 = v.w - mean;
    float ss = a0 * a0 + a1 * a1 + a2 * a2 + a3 * a3;
#pragma unroll
    for (int m = 1; m < 64; m <<= 1) ss += __shfl_xor(ss, m);
    if (lane == 0) p2[wid] = ss;
    __syncthreads();
    float var = (p2[0] + p2[1] + p2[2] + p2[3]) * (1.f / 1024.f);
    float rs = rsqrtf(var + 1e-5f);
    const float4 gg = ((const float4*)g)[t];
    const float4 bb = ((const float4*)be)[t];
    ushort4 ov;
    ov.x = f2bf(a0 * rs * gg.x + bb.x);
    ov.y = f2bf(a1 * rs * gg.y + bb.y);
    ov.z = f2bf(a2 * rs * gg.z + bb.z);
    ov.w = f2bf(a3 * rs * gg.w + bb.w);
    *(ushort4*)(h1 + (size_t)row * 1024 + t * 4) = ov;
  }
}

// ---------------- LayerNorm fp32 -> bf16, D=1024 (ln2) ----------------
__global__ __launch_bounds__(256) void ln_kernel(const float* __restrict__ x,
                                                 const float* __restrict__ g,
                                                 const float* __restrict__ be,
                                                 u16* __restrict__ out) {
  int row = blockIdx.x, t = threadIdx.x;
  const float4 v = ((const float4*)(x + (size_t)row * 1024))[t];
  float s = v.x + v.y + v.z + v.w;
#pragma unroll
  for (int m = 1; m < 64; m <<= 1) s += __shfl_xor(s, m);
  __shared__ float p1[4], p2[4];
  int wid = t >> 6, lane = t & 63;
  if (lane == 0) p1[wid] = s;
  __syncthreads();
  float mean = (p1[0] + p1[1] + p1[2] + p1[3]) * (1.f / 1024.f);
  float a0 = v.x - mean, a1 = v.y - mean, a2 = v.z - mean, a3 = v.w - mean;
  float ss = a0 * a0 + a1 * a1 + a2 * a2 + a3 * a3;
#pragma unroll
  for (int m = 1; m < 64; m <<= 1) ss += __shfl_xor(ss, m);
  if (lane == 0) p2[wid] = ss;
  __syncthreads();
  float var = (p2[0] + p2[1] + p2[2] + p2[3]) * (1.f / 1024.f);
  float rs = rsqrtf(var + 1e-5f);
  const float4 gg = ((const float4*)g)[t];
  const float4 bb = ((const float4*)be)[t];
  ushort4 ov;
  ov.x = f2bf(a0 * rs * gg.x + bb.x);
  ov.y = f2bf(a1 * rs * gg.y + bb.y);
  ov.z = f2bf(a2 * rs * gg.z + bb.z);
  ov.w = f2bf(a3 * rs * gg.w + bb.w);
  *(ushort4*)(out + (size_t)row * 1024 + t * 4) = ov;
}

// ======== m97-structure GEMM: 128x128, BK=64, single-buffer 32KB, XCD swizzle ====
// Proven 874-912 TF class at >=3 blocks/CU (m97/m102). Used for qkv (768 blocks
// = exactly 3/CU) and fc1 (1024 blocks).
template <int GELU_F, int HAS_RES, int OUT_F32, int OUT_BF16>
__global__ __launch_bounds__(256) void gemm97_kernel(
    const u16* __restrict__ A, const u16* __restrict__ Bt,
    const float* __restrict__ bias, const float* __restrict__ res,
    float* __restrict__ outf, u16* __restrict__ outb, int M, int N, int K, int nbn) {
  __shared__ u16 lA[128 * 64];
  __shared__ u16 lB[128 * 64];
  const int t = threadIdx.x, lane = t & 63, wid = t >> 6;
  const int wr = wid >> 1, wc = wid & 1;
  // bijective XCD swizzle (nwg % 8 == 0 for all our grids)
  const int nwg = gridDim.x;
  const int q = nwg >> 3, rm = nwg & 7;
  const int xcd = blockIdx.x & 7, oin = blockIdx.x >> 3;
  const int swz = (xcd < rm ? xcd * (q + 1) : rm * (q + 1) + (xcd - rm) * q) + oin;
  const int bm = swz / nbn, bn = swz % nbn;
  f32x4 acc[4][4] = {};
  const int nkt = K >> 6;

  for (int kt = 0; kt < nkt; ++kt) {
#pragma unroll
    for (int r = 0; r < 4; ++r) {
      int f = (r * 256 + t) * 16;                 // linear LDS byte offset
      int fs = f ^ (((f >> 7) & 7) << 4);         // inverse-swizzled source
      int row = fs >> 7;
      int kb = (fs & 127) >> 1;
      GLOAD16(A + (size_t)(bm * 128 + row) * K + kt * 64 + kb, ((char*)lA) + f);
      GLOAD16(Bt + (size_t)(bn * 128 + row) * K + kt * 64 + kb, ((char*)lB) + f);
    }
    __syncthreads();
#pragma unroll
    for (int kk = 0; kk < 2; ++kk) {
      bf16x8 af[4], bfr[4];
#pragma unroll
      for (int fm = 0; fm < 4; ++fm) {
        int row = wr * 64 + fm * 16 + (lane & 15);
        int k = kk * 32 + (lane >> 4) * 8;
        af[fm] = *(const bf16x8*)((const char*)lA + ((row * 128 + k * 2) ^ ((row & 7) << 4)));
      }
#pragma unroll
      for (int fn = 0; fn < 4; ++fn) {
        int row = wc * 64 + fn * 16 + (lane & 15);
        int k = kk * 32 + (lane >> 4) * 8;
        bfr[fn] = *(const bf16x8*)((const char*)lB + ((row * 128 + k * 2) ^ ((row & 7) << 4)));
      }
#pragma unroll
      for (int fm = 0; fm < 4; ++fm)
#pragma unroll
        for (int fn = 0; fn < 4; ++fn)
          acc[fm][fn] = __builtin_amdgcn_mfma_f32_16x16x32_bf16(af[fm], bfr[fn], acc[fm][fn], 0, 0, 0);
    }
    __syncthreads();
  }

#pragma unroll
  for (int fm = 0; fm < 4; ++fm) {
#pragma unroll
    for (int fn = 0; fn < 4; ++fn) {
      int col = bn * 128 + wc * 64 + fn * 16 + (lane & 15);
      float bcol = bias[col];
#pragma unroll
      for (int r = 0; r < 4; ++r) {
        int row = bm * 128 + wr * 64 + fm * 16 + (lane >> 4) * 4 + r;
        float v = acc[fm][fn][r] + bcol;
        if constexpr (GELU_F) v = gelu_fast(v);
        size_t idx = (size_t)row * N + col;
        if constexpr (HAS_RES) v += res[idx];
        if constexpr (OUT_F32) outf[idx] = v;
        if constexpr (OUT_BF16) outb[idx] = f2bf(v);
      }
    }
  }
}

// ---------------- 2-phase dbuf GEMM, 128xBN (BN=32 for proj/fc2: 4 blocks/CU) ----
template <int BN, int GELU_F, int HAS_RES, int OUT_F32, int OUT_BF16>
__global__ __launch_bounds__(256) void gemm_kernel(
    const u16* __restrict__ A, const u16* __restrict__ Bt,
    const float* __restrict__ bias, const float* __restrict__ res,
    float* __restrict__ outf, u16* __restrict__ outb, int M, int N, int K) {
  __shared__ u16 lA[2][128 * 64];
  __shared__ u16 lB[2][BN * 64];
  const int t = threadIdx.x, lane = t & 63, wid = t >> 6;
  const int bm = blockIdx.x, bn = blockIdx.y;
  constexpr int FM = (BN == 128) ? 4 : 2;
  constexpr int FN = (BN == 128) ? 4 : (BN / 16);
  const int wr = (BN == 128) ? (wid >> 1) : wid;
  const int wc = (BN == 128) ? (wid & 1) : 0;
  f32x4 acc[FM][FN] = {};

  const int nkt = K >> 6;

  auto stage = [&](int buf, int kt) {
#pragma unroll
    for (int r = 0; r < 4; ++r) {
      int f = (r * 256 + t) * 16;
      int fs = f ^ (((f >> 7) & 7) << 4);
      int row = fs >> 7;
      int kb = (fs & 127) >> 1;
      GLOAD16(A + (size_t)(bm * 128 + row) * K + kt * 64 + kb,
              ((char*)&lA[buf][0]) + f);
    }
#pragma unroll
    for (int r = 0; r < BN / 32; ++r) {
      int f = (r * 256 + t) * 16;
      int fs = f ^ (((f >> 7) & 7) << 4);
      int row = fs >> 7;
      int kb = (fs & 127) >> 1;
      GLOAD16(Bt + (size_t)(bn * BN + row) * K + kt * 64 + kb,
              ((char*)&lB[buf][0]) + f);
    }
  };

  stage(0, 0);
  __syncthreads();

  for (int kt = 0; kt < nkt; ++kt) {
    const int cur = kt & 1;
    if (kt + 1 < nkt) stage(cur ^ 1, kt + 1);
#pragma unroll
    for (int kk = 0; kk < 2; ++kk) {
      bf16x8 af[FM], bfr[FN];
#pragma unroll
      for (int fm = 0; fm < FM; ++fm) {
        int row = wr * (FM * 16) + fm * 16 + (lane & 15);
        int k = kk * 32 + (lane >> 4) * 8;
        af[fm] = *(const bf16x8*)((const char*)&lA[cur][0] + ((row * 128 + k * 2) ^ ((row & 7) << 4)));
      }
#pragma unroll
      for (int fn = 0; fn < FN; ++fn) {
        int row = wc * 64 + fn * 16 + (lane & 15);
        int k = kk * 32 + (lane >> 4) * 8;
        bfr[fn] = *(const bf16x8*)((const char*)&lB[cur][0] + ((row * 128 + k * 2) ^ ((row & 7) << 4)));
      }
#pragma unroll
      for (int fm = 0; fm < FM; ++fm)
#pragma unroll
        for (int fn = 0; fn < FN; ++fn)
          acc[fm][fn] = __builtin_amdgcn_mfma_f32_16x16x32_bf16(af[fm], bfr[fn], acc[fm][fn], 0, 0, 0);
    }
    __syncthreads();
  }

#pragma unroll
  for (int fm = 0; fm < FM; ++fm) {
#pragma unroll
    for (int fn = 0; fn < FN; ++fn) {
      int col = bn * BN + wc * 64 + fn * 16 + (lane & 15);
      float bcol = bias[col];
#pragma unroll
      for (int r = 0; r < 4; ++r) {
        int row = bm * 128 + wr * (FM * 16) + fm * 16 + (lane >> 4) * 4 + r;
        float v = acc[fm][fn][r] + bcol;
        if constexpr (GELU_F) v = gelu_fast(v);
        size_t idx = (size_t)row * N + col;
        if constexpr (HAS_RES) v += res[idx];
        if constexpr (OUT_F32) outf[idx] = v;
        if constexpr (OUT_BF16) outb[idx] = f2bf(v);
      }
    }
  }
}

// ---------------- attention: ALiBi sliding-window causal, MFMA ----------------
__global__ __launch_bounds__(256) void attn_kernel(const u16* __restrict__ qkv,
                                                   u16* __restrict__ o) {
  __shared__ u16 kvbuf[22016];      // 44 KB: K[320][64] swizzled, then V^T[64][344]
  __shared__ u16 lP[4][16 * 296];   // per-wave P, 37 KB (total 80 KB -> 2 blocks/CU)
  u16* lK = kvbuf;
  u16* lV = kvbuf;
  const int t = threadIdx.x, lane = t & 63, w = t >> 6;
  const int qtile = blockIdx.x, bh = blockIdx.y, b = bh >> 4, h = bh & 15;
  const int kbase = qtile * 64 - 256;
  const size_t bq = (size_t)b * 2048 * 3072;
  const float NEGBIG = -1e30f;

  for (int r = 0; r < 10; ++r) {
    int jl = r * 32 + (t >> 3);
    int d0 = (t & 7) * 8;
    int jg = kbase + jl;
    uint4 kv;
    if (jg >= 0 && jg < 2048)
      kv = *(const uint4*)(qkv + bq + (size_t)jg * 3072 + 1024 + h * 64 + d0);
    else
      kv = make_uint4(0, 0, 0, 0);
    *(uint4*)((char*)lK + ((jl * 128 + d0 * 2) ^ ((jl & 7) << 4))) = kv;
  }
  __syncthreads();

  const int i0 = qtile * 64 + w * 16;
  const int q15 = lane & 15, grp = lane >> 4;
  const u16* qrow = qkv + bq + (size_t)(i0 + q15) * 3072 + h * 64;
  bf16x8 qf0 = *(const bf16x8*)(qrow + grp * 8);
  bf16x8 qf1 = *(const bf16x8*)(qrow + 32 + grp * 8);

  f32x4 st[17];
#pragma unroll
  for (int tt = 0; tt < 17; ++tt) {
    st[tt] = f32x4{0.f, 0.f, 0.f, 0.f};
    int klb = w * 16 + tt * 16;
#pragma unroll
    for (int kk = 0; kk < 2; ++kk) {
      int row = klb + q15;
      int k = kk * 32 + grp * 8;
      bf16x8 kf = *(const bf16x8*)((const char*)lK + ((row * 128 + k * 2) ^ ((row & 7) << 4)));
      st[tt] = __builtin_amdgcn_mfma_f32_16x16x32_bf16(kf, (kk ? qf1 : qf0), st[tt], 0, 0, 0);
    }
  }

  const float slope = exp2f(-0.5f * (float)(h + 1));
  const int qg = i0 + q15;
  float mx = NEGBIG;
#pragma unroll
  for (int tt = 0; tt < 17; ++tt) {
    int kb = kbase + w * 16 + tt * 16;
#pragma unroll
    for (int r = 0; r < 4; ++r) {
      int key = kb + grp * 4 + r;
      float s = st[tt][r] * 0.125f + slope * (float)(key - qg);
      bool valid = (key >= 0) && (key <= qg) && (qg - key < 256);
      s = valid ? s : NEGBIG;
      st[tt][r] = s;
      mx = fmaxf(mx, s);
    }
  }
  mx = fmaxf(mx, __shfl_xor(mx, 16));
  mx = fmaxf(mx, __shfl_xor(mx, 32));
  float sum = 0.f;
#pragma unroll
  for (int tt = 0; tt < 17; ++tt)
#pragma unroll
    for (int r = 0; r < 4; ++r) {
      float p = __expf(st[tt][r] - mx);
      st[tt][r] = p;
      sum += p;
    }
  sum += __shfl_xor(sum, 16);
  sum += __shfl_xor(sum, 32);
  const float inv = 1.0f / sum;

  u16* Pw = &lP[w][0];
#pragma unroll
  for (int tt = 0; tt < 17; ++tt) {
    unsigned u0 = ((unsigned)f2bf(st[tt][1]) << 16) | f2bf(st[tt][0]);
    unsigned u1 = ((unsigned)f2bf(st[tt][3]) << 16) | f2bf(st[tt][2]);
    uint2 uu; uu.x = u0; uu.y = u1;
    *(uint2*)(Pw + q15 * 296 + tt * 16 + grp * 4) = uu;
  }
  { uint2 z; z.x = 0; z.y = 0; *(uint2*)(Pw + q15 * 296 + 272 + grp * 4) = z; }

  __syncthreads();   // lK reads done -> overwrite with V

  for (int r = 0; r < 11; ++r) {
    int jl = r * 32 + (t >> 3);
    int d0 = (t & 7) * 8;
    int jg = kbase + jl;
    if (jl < 336) {
      uint4 vv;
      if (jg >= 0 && jg < 2048)
        vv = *(const uint4*)(qkv + bq + (size_t)jg * 3072 + 2048 + h * 64 + d0);
      else
        vv = make_uint4(0, 0, 0, 0);
      const u16* vs = (const u16*)&vv;
#pragma unroll
      for (int u = 0; u < 8; ++u) lV[(d0 + u) * 344 + jl] = vs[u];
    }
  }
  __syncthreads();

  f32x4 ot[4] = {};
#pragma unroll
  for (int c = 0; c < 9; ++c) {
    bf16x8 pf = *(const bf16x8*)(Pw + q15 * 296 + c * 32 + grp * 8);
#pragma unroll
    for (int hb = 0; hb < 4; ++hb) {
      bf16x8 vf = *(const bf16x8*)(lV + (hb * 16 + q15) * 344 + w * 16 + c * 32 + grp * 8);
      ot[hb] = __builtin_amdgcn_mfma_f32_16x16x32_bf16(vf, pf, ot[hb], 0, 0, 0);
    }
  }

#pragma unroll
  for (int hb = 0; hb < 4; ++hb) {
    ushort4 ov;
    ov.x = f2bf(ot[hb][0] * inv);
    ov.y = f2bf(ot[hb][1] * inv);
    ov.z = f2bf(ot[hb][2] * inv);
    ov.w = f2bf(ot[hb][3] * inv);
    *(ushort4*)(o + (size_t)(b * 2048 + i0 + q15) * 1024 + h * 64 + hb * 16 + grp * 4) = ov;
  }
}

// ---------------- launcher ----------------
// ws (aliased by liveness): 64 MB total.
//   [0,25165824): transposed weights | [25165824,58720256): BIG = qkvb then ff1
//   [58720256,67108864): SMALL = h1 / obuf / h2 | x1 lives in d_out.
extern "C" void kernel_launch(void* const* d_in, const int* in_sizes, int n_in,
                              void* d_out, int out_size, void* d_ws, size_t ws_size,
                              hipStream_t stream) {
  const float* x      = (const float*)d_in[0];
  const float* qkv_w  = (const float*)d_in[1];
  const float* qkv_b  = (const float*)d_in[2];
  const float* proj_w = (const float*)d_in[3];
  const float* proj_b = (const float*)d_in[4];
  const float* ln1_g  = (const float*)d_in[5];
  const float* ln1_b  = (const float*)d_in[6];
  const float* ln2_g  = (const float*)d_in[7];
  const float* ln2_b  = (const float*)d_in[8];
  const float* fc1_w  = (const float*)d_in[9];
  const float* fc1_b  = (const float*)d_in[10];
  const float* fc2_w  = (const float*)d_in[11];
  const float* fc2_b  = (const float*)d_in[12];
  float* out = (float*)d_out;

  char* ws = (char*)d_ws;
  u16* qkvw_t  = (u16*)(ws);
  u16* projw_t = (u16*)(ws + 6291456);
  u16* fc1w_t  = (u16*)(ws + 8388608);
  u16* fc2w_t  = (u16*)(ws + 16777216);
  char* BIG    = ws + 25165824;
  char* SMALL  = ws + 58720256;
  u16* qkvb = (u16*)BIG;
  u16* ff1  = (u16*)BIG;
  u16* h1   = (u16*)SMALL;
  u16* obuf = (u16*)SMALL;
  u16* h2   = (u16*)SMALL;
  float* x1 = out;

  // fused: 4 weight transposes + LN1 (independent work, one launch)
  pre_kernel<<<16384, 256, 0, stream>>>(qkv_w, proj_w, fc1_w, fc2_w,
                                        qkvw_t, projw_t, fc1w_t, fc2w_t,
                                        x, ln1_g, ln1_b, h1);
  // qkv: 768 blocks = exactly 3/CU (m97 sweet spot)
  gemm97_kernel<0, 0, 0, 1><<<768, 256, 0, stream>>>(h1, qkvw_t, qkv_b, nullptr, nullptr, qkvb, 4096, 3072, 1024, 24);
  attn_kernel<<<dim3(32, 32), 256, 0, stream>>>(qkvb, obuf);
  // proj: BN=32, 1024 blocks = 4/CU
  gemm_kernel<32, 0, 1, 1, 0><<<dim3(32, 32), 256, 0, stream>>>(obuf, projw_t, proj_b, x, x1, nullptr, 4096, 1024, 1024);
  ln_kernel<<<4096, 256, 0, stream>>>(x1, ln2_g, ln2_b, h2);
  // fc1: 1024 blocks, 3/CU
  gemm97_kernel<1, 0, 0, 1><<<1024, 256, 0, stream>>>(h2, fc1w_t, fc1_b, nullptr, nullptr, ff1, 4096, 4096, 1024, 32);
  // fc2: BN=32, 1024 blocks = 4/CU
  gemm_kernel<32, 0, 1, 1, 0><<<dim3(32, 32), 256, 0, stream>>>(ff1, fc2w_t, fc2_b, x1, out, nullptr, 4096, 1024, 4096);
}

// Round 10
// 313.740 us; speedup vs baseline: 1.0814x; 1.0814x over previous
//
#include <hip/hip_runtime.h>
#include <stdint.h>

typedef unsigned short u16;
typedef __attribute__((ext_vector_type(8))) short bf16x8;
typedef __attribute__((ext_vector_type(4))) float f32x4;

__device__ __forceinline__ u16 f2bf(float f) {
  union { float f; unsigned u; } x; x.f = f;
  unsigned r = x.u + 0x7fffu + ((x.u >> 16) & 1u);
  return (u16)(r >> 16);
}

__device__ __forceinline__ float gelu_fast(float v) {
  float y = 0.7978845608f * (v + 0.044715f * v * v * v);
  float e = __expf(2.0f * y);
  float th = 1.0f - 2.0f / (e + 1.0f);
  return 0.5f * v * (1.0f + th);
}

#define GLOAD16(g, l) __builtin_amdgcn_global_load_lds( \
    (const __attribute__((address_space(1))) unsigned int*)(g), \
    (__attribute__((address_space(3))) unsigned int*)(l), 16, 0, 0)

// ---------------- fused pre-pass: 4 weight transposes + LN1 ----------------
__global__ __launch_bounds__(256) void pre_kernel(
    const float* __restrict__ qkv_w, const float* __restrict__ proj_w,
    const float* __restrict__ fc1_w, const float* __restrict__ fc2_w,
    u16* __restrict__ qkvw_t, u16* __restrict__ projw_t,
    u16* __restrict__ fc1w_t, u16* __restrict__ fc2w_t,
    const float* __restrict__ x, const float* __restrict__ g,
    const float* __restrict__ be, u16* __restrict__ h1) {
  __shared__ float tile[32][33];
  __shared__ float p1[4], p2[4];
  const int bid = blockIdx.x, t = threadIdx.x;
  if (bid < 12288) {
    const float* W; u16* Wt; int K, N, base, nb;
    if (bid < 3072)      { W = qkv_w;  Wt = qkvw_t;  K = 1024; N = 3072; base = 0;    nb = 96; }
    else if (bid < 4096) { W = proj_w; Wt = projw_t; K = 1024; N = 1024; base = 3072; nb = 32; }
    else if (bid < 8192) { W = fc1_w;  Wt = fc1w_t;  K = 1024; N = 4096; base = 4096; nb = 128; }
    else                 { W = fc2_w;  Wt = fc2w_t;  K = 4096; N = 1024; base = 8192; nb = 32; }
    int r = bid - base;
    int n0 = (r % nb) * 32, k0 = (r / nb) * 32;
    int tx = t & 31, ty = t >> 5;
#pragma unroll
    for (int i = 0; i < 32; i += 8)
      tile[ty + i][tx] = W[(size_t)(k0 + ty + i) * N + n0 + tx];
    __syncthreads();
#pragma unroll
    for (int i = 0; i < 32; i += 8)
      Wt[(size_t)(n0 + ty + i) * K + k0 + tx] = f2bf(tile[tx][ty + i]);
  } else {
    int row = bid - 12288;
    const float4 v = ((const float4*)(x + (size_t)row * 1024))[t];
    float s = v.x + v.y + v.z + v.w;
#pragma unroll
    for (int m = 1; m < 64; m <<= 1) s += __shfl_xor(s, m);
    int wid = t >> 6, lane = t & 63;
    if (lane == 0) p1[wid] = s;
    __syncthreads();
    float mean = (p1[0] + p1[1] + p1[2] + p1[3]) * (1.f / 1024.f);
    float a0 = v.x - mean, a1 = v.y - mean, a2 = v.z - mean, a3 = v.w - mean;
    float ss = a0 * a0 + a1 * a1 + a2 * a2 + a3 * a3;
#pragma unroll
    for (int m = 1; m < 64; m <<= 1) ss += __shfl_xor(ss, m);
    if (lane == 0) p2[wid] = ss;
    __syncthreads();
    float var = (p2[0] + p2[1] + p2[2] + p2[3]) * (1.f / 1024.f);
    float rs = rsqrtf(var + 1e-5f);
    const float4 gg = ((const float4*)g)[t];
    const float4 bb = ((const float4*)be)[t];
    ushort4 ov;
    ov.x = f2bf(a0 * rs * gg.x + bb.x);
    ov.y = f2bf(a1 * rs * gg.y + bb.y);
    ov.z = f2bf(a2 * rs * gg.z + bb.z);
    ov.w = f2bf(a3 * rs * gg.w + bb.w);
    *(ushort4*)(h1 + (size_t)row * 1024 + t * 4) = ov;
  }
}

// ---------------- LayerNorm fp32 -> bf16, D=1024 (ln2) ----------------
__global__ __launch_bounds__(256) void ln_kernel(const float* __restrict__ x,
                                                 const float* __restrict__ g,
                                                 const float* __restrict__ be,
                                                 u16* __restrict__ out) {
  int row = blockIdx.x, t = threadIdx.x;
  const float4 v = ((const float4*)(x + (size_t)row * 1024))[t];
  float s = v.x + v.y + v.z + v.w;
#pragma unroll
  for (int m = 1; m < 64; m <<= 1) s += __shfl_xor(s, m);
  __shared__ float p1[4], p2[4];
  int wid = t >> 6, lane = t & 63;
  if (lane == 0) p1[wid] = s;
  __syncthreads();
  float mean = (p1[0] + p1[1] + p1[2] + p1[3]) * (1.f / 1024.f);
  float a0 = v.x - mean, a1 = v.y - mean, a2 = v.z - mean, a3 = v.w - mean;
  float ss = a0 * a0 + a1 * a1 + a2 * a2 + a3 * a3;
#pragma unroll
  for (int m = 1; m < 64; m <<= 1) ss += __shfl_xor(ss, m);
  if (lane == 0) p2[wid] = ss;
  __syncthreads();
  float var = (p2[0] + p2[1] + p2[2] + p2[3]) * (1.f / 1024.f);
  float rs = rsqrtf(var + 1e-5f);
  const float4 gg = ((const float4*)g)[t];
  const float4 bb = ((const float4*)be)[t];
  ushort4 ov;
  ov.x = f2bf(a0 * rs * gg.x + bb.x);
  ov.y = f2bf(a1 * rs * gg.y + bb.y);
  ov.z = f2bf(a2 * rs * gg.z + bb.z);
  ov.w = f2bf(a3 * rs * gg.w + bb.w);
  *(ushort4*)(out + (size_t)row * 1024 + t * 4) = ov;
}

// ======== wide-wave GEMM: 256x128 block, 4 waves of 128x64, BK=64 ========
// LDS reads/MFMA = 0.375 (vs 0.5 at 64x64/wave) -> attacks the measured
// LDS-read-throughput plateau. Single-buffer 48 KB, 2 blocks/CU (VGPR-bound),
// both-sides XOR swizzle, bijective XCD swizzle. bf16 out + bias (+GELU).
template <int GELU_F>
__global__ __launch_bounds__(256, 2) void gemmw_kernel(
    const u16* __restrict__ A, const u16* __restrict__ Bt,
    const float* __restrict__ bias, u16* __restrict__ outb,
    int M, int N, int K, int nbn) {
  __shared__ u16 lA[256 * 64];   // 32 KB
  __shared__ u16 lB[128 * 64];   // 16 KB
  const int t = threadIdx.x, lane = t & 63, wid = t >> 6;
  const int wm = wid >> 1, wn = wid & 1;          // 2x2 waves, each 128x64
  const int q15 = lane & 15, grp = lane >> 4;
  // bijective XCD swizzle (nwg % 8 == 0 for our grids)
  const int nwg = gridDim.x;
  const int qq = nwg >> 3, rm = nwg & 7;
  const int xcd = blockIdx.x & 7, oin = blockIdx.x >> 3;
  const int swz = (xcd < rm ? xcd * (qq + 1) : rm * (qq + 1) + (xcd - rm) * qq) + oin;
  const int bm = swz / nbn, bn = swz % nbn;

  f32x4 acc[8][4] = {};
  const int nkt = K >> 6;

  for (int kt = 0; kt < nkt; ++kt) {
    // stage A (256x64) + B (128x64), linear dest, inverse-swizzled source
#pragma unroll
    for (int r = 0; r < 8; ++r) {
      int f = (r * 256 + t) * 16;
      int fs = f ^ (((f >> 7) & 7) << 4);
      int row = fs >> 7, kb = (fs & 127) >> 1;
      GLOAD16(A + (size_t)(bm * 256 + row) * K + kt * 64 + kb, ((char*)lA) + f);
    }
#pragma unroll
    for (int r = 0; r < 4; ++r) {
      int f = (r * 256 + t) * 16;
      int fs = f ^ (((f >> 7) & 7) << 4);
      int row = fs >> 7, kb = (fs & 127) >> 1;
      GLOAD16(Bt + (size_t)(bn * 128 + row) * K + kt * 64 + kb, ((char*)lB) + f);
    }
    __syncthreads();
#pragma unroll
    for (int kk = 0; kk < 2; ++kk) {
      const int k = kk * 32 + grp * 8;
      bf16x8 bfr[4];
#pragma unroll
      for (int fn = 0; fn < 4; ++fn) {
        int row = wn * 64 + fn * 16 + q15;
        bfr[fn] = *(const bf16x8*)((const char*)lB + ((row * 128 + k * 2) ^ ((row & 7) << 4)));
      }
#pragma unroll
      for (int j = 0; j < 8; ++j) {
        int row = wm * 128 + j * 16 + q15;
        bf16x8 af = *(const bf16x8*)((const char*)lA + ((row * 128 + k * 2) ^ ((row & 7) << 4)));
#pragma unroll
        for (int fn = 0; fn < 4; ++fn)
          acc[j][fn] = __builtin_amdgcn_mfma_f32_16x16x32_bf16(af, bfr[fn], acc[j][fn], 0, 0, 0);
      }
    }
    __syncthreads();
  }

#pragma unroll
  for (int j = 0; j < 8; ++j) {
#pragma unroll
    for (int fn = 0; fn < 4; ++fn) {
      int col = bn * 128 + wn * 64 + fn * 16 + q15;
      float bcol = bias[col];
#pragma unroll
      for (int r = 0; r < 4; ++r) {
        int row = bm * 256 + wm * 128 + j * 16 + grp * 4 + r;
        float v = acc[j][fn][r] + bcol;
        if constexpr (GELU_F) v = gelu_fast(v);
        outb[(size_t)row * N + col] = f2bf(v);
      }
    }
  }
}

// ---------------- 2-phase dbuf GEMM, 128xBN (BN=64 for proj/fc2: proven 586 TF) ---
template <int BN, int GELU_F, int HAS_RES, int OUT_F32, int OUT_BF16>
__global__ __launch_bounds__(256) void gemm_kernel(
    const u16* __restrict__ A, const u16* __restrict__ Bt,
    const float* __restrict__ bias, const float* __restrict__ res,
    float* __restrict__ outf, u16* __restrict__ outb, int M, int N, int K) {
  __shared__ u16 lA[2][128 * 64];
  __shared__ u16 lB[2][BN * 64];
  const int t = threadIdx.x, lane = t & 63, wid = t >> 6;
  const int bm = blockIdx.x, bn = blockIdx.y;
  constexpr int FM = (BN == 128) ? 4 : 2;
  constexpr int FN = (BN == 128) ? 4 : (BN / 16);
  const int wr = (BN == 128) ? (wid >> 1) : wid;
  const int wc = (BN == 128) ? (wid & 1) : 0;
  f32x4 acc[FM][FN] = {};

  const int nkt = K >> 6;

  auto stage = [&](int buf, int kt) {
#pragma unroll
    for (int r = 0; r < 4; ++r) {
      int f = (r * 256 + t) * 16;
      int fs = f ^ (((f >> 7) & 7) << 4);
      int row = fs >> 7;
      int kb = (fs & 127) >> 1;
      GLOAD16(A + (size_t)(bm * 128 + row) * K + kt * 64 + kb,
              ((char*)&lA[buf][0]) + f);
    }
#pragma unroll
    for (int r = 0; r < BN / 32; ++r) {
      int f = (r * 256 + t) * 16;
      int fs = f ^ (((f >> 7) & 7) << 4);
      int row = fs >> 7;
      int kb = (fs & 127) >> 1;
      GLOAD16(Bt + (size_t)(bn * BN + row) * K + kt * 64 + kb,
              ((char*)&lB[buf][0]) + f);
    }
  };

  stage(0, 0);
  __syncthreads();

  for (int kt = 0; kt < nkt; ++kt) {
    const int cur = kt & 1;
    if (kt + 1 < nkt) stage(cur ^ 1, kt + 1);
#pragma unroll
    for (int kk = 0; kk < 2; ++kk) {
      bf16x8 af[FM], bfr[FN];
#pragma unroll
      for (int fm = 0; fm < FM; ++fm) {
        int row = wr * (FM * 16) + fm * 16 + (lane & 15);
        int k = kk * 32 + (lane >> 4) * 8;
        af[fm] = *(const bf16x8*)((const char*)&lA[cur][0] + ((row * 128 + k * 2) ^ ((row & 7) << 4)));
      }
#pragma unroll
      for (int fn = 0; fn < FN; ++fn) {
        int row = wc * 64 + fn * 16 + (lane & 15);
        int k = kk * 32 + (lane >> 4) * 8;
        bfr[fn] = *(const bf16x8*)((const char*)&lB[cur][0] + ((row * 128 + k * 2) ^ ((row & 7) << 4)));
      }
#pragma unroll
      for (int fm = 0; fm < FM; ++fm)
#pragma unroll
        for (int fn = 0; fn < FN; ++fn)
          acc[fm][fn] = __builtin_amdgcn_mfma_f32_16x16x32_bf16(af[fm], bfr[fn], acc[fm][fn], 0, 0, 0);
    }
    __syncthreads();
  }

#pragma unroll
  for (int fm = 0; fm < FM; ++fm) {
#pragma unroll
    for (int fn = 0; fn < FN; ++fn) {
      int col = bn * BN + wc * 64 + fn * 16 + (lane & 15);
      float bcol = bias[col];
#pragma unroll
      for (int r = 0; r < 4; ++r) {
        int row = bm * 128 + wr * (FM * 16) + fm * 16 + (lane >> 4) * 4 + r;
        float v = acc[fm][fn][r] + bcol;
        if constexpr (GELU_F) v = gelu_fast(v);
        size_t idx = (size_t)row * N + col;
        if constexpr (HAS_RES) v += res[idx];
        if constexpr (OUT_F32) outf[idx] = v;
        if constexpr (OUT_BF16) outb[idx] = f2bf(v);
      }
    }
  }
}

// ---------------- attention: ALiBi sliding-window causal, MFMA ----------------
__global__ __launch_bounds__(256) void attn_kernel(const u16* __restrict__ qkv,
                                                   u16* __restrict__ o) {
  __shared__ u16 kvbuf[22016];      // 44 KB: K[320][64] swizzled, then V^T[64][344]
  __shared__ u16 lP[4][16 * 296];   // per-wave P, 37 KB (total 80 KB -> 2 blocks/CU)
  u16* lK = kvbuf;
  u16* lV = kvbuf;
  const int t = threadIdx.x, lane = t & 63, w = t >> 6;
  const int qtile = blockIdx.x, bh = blockIdx.y, b = bh >> 4, h = bh & 15;
  const int kbase = qtile * 64 - 256;
  const size_t bq = (size_t)b * 2048 * 3072;
  const float NEGBIG = -1e30f;

  for (int r = 0; r < 10; ++r) {
    int jl = r * 32 + (t >> 3);
    int d0 = (t & 7) * 8;
    int jg = kbase + jl;
    uint4 kv;
    if (jg >= 0 && jg < 2048)
      kv = *(const uint4*)(qkv + bq + (size_t)jg * 3072 + 1024 + h * 64 + d0);
    else
      kv = make_uint4(0, 0, 0, 0);
    *(uint4*)((char*)lK + ((jl * 128 + d0 * 2) ^ ((jl & 7) << 4))) = kv;
  }
  __syncthreads();

  const int i0 = qtile * 64 + w * 16;
  const int q15 = lane & 15, grp = lane >> 4;
  const u16* qrow = qkv + bq + (size_t)(i0 + q15) * 3072 + h * 64;
  bf16x8 qf0 = *(const bf16x8*)(qrow + grp * 8);
  bf16x8 qf1 = *(const bf16x8*)(qrow + 32 + grp * 8);

  f32x4 st[17];
#pragma unroll
  for (int tt = 0; tt < 17; ++tt) {
    st[tt] = f32x4{0.f, 0.f, 0.f, 0.f};
    int klb = w * 16 + tt * 16;
#pragma unroll
    for (int kk = 0; kk < 2; ++kk) {
      int row = klb + q15;
      int k = kk * 32 + grp * 8;
      bf16x8 kf = *(const bf16x8*)((const char*)lK + ((row * 128 + k * 2) ^ ((row & 7) << 4)));
      st[tt] = __builtin_amdgcn_mfma_f32_16x16x32_bf16(kf, (kk ? qf1 : qf0), st[tt], 0, 0, 0);
    }
  }

  const float slope = exp2f(-0.5f * (float)(h + 1));
  const int qg = i0 + q15;
  float mx = NEGBIG;
#pragma unroll
  for (int tt = 0; tt < 17; ++tt) {
    int kb = kbase + w * 16 + tt * 16;
#pragma unroll
    for (int r = 0; r < 4; ++r) {
      int key = kb + grp * 4 + r;
      float s = st[tt][r] * 0.125f + slope * (float)(key - qg);
      bool valid = (key >= 0) && (key <= qg) && (qg - key < 256);
      s = valid ? s : NEGBIG;
      st[tt][r] = s;
      mx = fmaxf(mx, s);
    }
  }
  mx = fmaxf(mx, __shfl_xor(mx, 16));
  mx = fmaxf(mx, __shfl_xor(mx, 32));
  float sum = 0.f;
#pragma unroll
  for (int tt = 0; tt < 17; ++tt)
#pragma unroll
    for (int r = 0; r < 4; ++r) {
      float p = __expf(st[tt][r] - mx);
      st[tt][r] = p;
      sum += p;
    }
  sum += __shfl_xor(sum, 16);
  sum += __shfl_xor(sum, 32);
  const float inv = 1.0f / sum;

  u16* Pw = &lP[w][0];
#pragma unroll
  for (int tt = 0; tt < 17; ++tt) {
    unsigned u0 = ((unsigned)f2bf(st[tt][1]) << 16) | f2bf(st[tt][0]);
    unsigned u1 = ((unsigned)f2bf(st[tt][3]) << 16) | f2bf(st[tt][2]);
    uint2 uu; uu.x = u0; uu.y = u1;
    *(uint2*)(Pw + q15 * 296 + tt * 16 + grp * 4) = uu;
  }
  { uint2 z; z.x = 0; z.y = 0; *(uint2*)(Pw + q15 * 296 + 272 + grp * 4) = z; }

  __syncthreads();   // lK reads done -> overwrite with V

  for (int r = 0; r < 11; ++r) {
    int jl = r * 32 + (t >> 3);
    int d0 = (t & 7) * 8;
    int jg = kbase + jl;
    if (jl < 336) {
      uint4 vv;
      if (jg >= 0 && jg < 2048)
        vv = *(const uint4*)(qkv + bq + (size_t)jg * 3072 + 2048 + h * 64 + d0);
      else
        vv = make_uint4(0, 0, 0, 0);
      const u16* vs = (const u16*)&vv;
#pragma unroll
      for (int u = 0; u < 8; ++u) lV[(d0 + u) * 344 + jl] = vs[u];
    }
  }
  __syncthreads();

  f32x4 ot[4] = {};
#pragma unroll
  for (int c = 0; c < 9; ++c) {
    bf16x8 pf = *(const bf16x8*)(Pw + q15 * 296 + c * 32 + grp * 8);
#pragma unroll
    for (int hb = 0; hb < 4; ++hb) {
      bf16x8 vf = *(const bf16x8*)(lV + (hb * 16 + q15) * 344 + w * 16 + c * 32 + grp * 8);
      ot[hb] = __builtin_amdgcn_mfma_f32_16x16x32_bf16(vf, pf, ot[hb], 0, 0, 0);
    }
  }

#pragma unroll
  for (int hb = 0; hb < 4; ++hb) {
    ushort4 ov;
    ov.x = f2bf(ot[hb][0] * inv);
    ov.y = f2bf(ot[hb][1] * inv);
    ov.z = f2bf(ot[hb][2] * inv);
    ov.w = f2bf(ot[hb][3] * inv);
    *(ushort4*)(o + (size_t)(b * 2048 + i0 + q15) * 1024 + h * 64 + hb * 16 + grp * 4) = ov;
  }
}

// ---------------- launcher ----------------
// ws (aliased by liveness): 64 MB total.
//   [0,25165824): transposed weights | [25165824,58720256): BIG = qkvb then ff1
//   [58720256,67108864): SMALL = h1 / obuf / h2 | x1 lives in d_out.
extern "C" void kernel_launch(void* const* d_in, const int* in_sizes, int n_in,
                              void* d_out, int out_size, void* d_ws, size_t ws_size,
                              hipStream_t stream) {
  const float* x      = (const float*)d_in[0];
  const float* qkv_w  = (const float*)d_in[1];
  const float* qkv_b  = (const float*)d_in[2];
  const float* proj_w = (const float*)d_in[3];
  const float* proj_b = (const float*)d_in[4];
  const float* ln1_g  = (const float*)d_in[5];
  const float* ln1_b  = (const float*)d_in[6];
  const float* ln2_g  = (const float*)d_in[7];
  const float* ln2_b  = (const float*)d_in[8];
  const float* fc1_w  = (const float*)d_in[9];
  const float* fc1_b  = (const float*)d_in[10];
  const float* fc2_w  = (const float*)d_in[11];
  const float* fc2_b  = (const float*)d_in[12];
  float* out = (float*)d_out;

  char* ws = (char*)d_ws;
  u16* qkvw_t  = (u16*)(ws);
  u16* projw_t = (u16*)(ws + 6291456);
  u16* fc1w_t  = (u16*)(ws + 8388608);
  u16* fc2w_t  = (u16*)(ws + 16777216);
  char* BIG    = ws + 25165824;
  char* SMALL  = ws + 58720256;
  u16* qkvb = (u16*)BIG;
  u16* ff1  = (u16*)BIG;
  u16* h1   = (u16*)SMALL;
  u16* obuf = (u16*)SMALL;
  u16* h2   = (u16*)SMALL;
  float* x1 = out;

  pre_kernel<<<16384, 256, 0, stream>>>(qkv_w, proj_w, fc1_w, fc2_w,
                                        qkvw_t, projw_t, fc1w_t, fc2w_t,
                                        x, ln1_g, ln1_b, h1);
  // qkv: 256x128 wide-wave, 16x24 = 384 blocks
  gemmw_kernel<0><<<384, 256, 0, stream>>>(h1, qkvw_t, qkv_b, qkvb, 4096, 3072, 1024, 24);
  attn_kernel<<<dim3(32, 32), 256, 0, stream>>>(qkvb, obuf);
  // proj: BN=64 2-phase (round-6 proven)
  gemm_kernel<64, 0, 1, 1, 0><<<dim3(32, 16), 256, 0, stream>>>(obuf, projw_t, proj_b, x, x1, nullptr, 4096, 1024, 1024);
  ln_kernel<<<4096, 256, 0, stream>>>(x1, ln2_g, ln2_b, h2);
  // fc1: 256x128 wide-wave, 16x32 = 512 blocks
  gemmw_kernel<1><<<512, 256, 0, stream>>>(h2, fc1w_t, fc1_b, ff1, 4096, 4096, 1024, 32);
  // fc2: BN=64 2-phase (round-6 proven)
  gemm_kernel<64, 0, 1, 1, 0><<<dim3(32, 16), 256, 0, stream>>>(ff1, fc2w_t, fc2_b, x1, out, nullptr, 4096, 1024, 4096);
}